// Round 18
// baseline (467.140 us; speedup 1.0000x reference)
//
#include <hip/hip_runtime.h>
#include <hip/hip_bf16.h>

#define ALPHA 0.2f
#define LOG2E 1.4426950408889634f
#define MAGIC 0x7F3A9C51u

typedef __attribute__((ext_vector_type(8))) short bf16x8;
typedef __attribute__((ext_vector_type(4))) float f32x4;
typedef __attribute__((ext_vector_type(4))) int i32x4;
typedef __attribute__((ext_vector_type(2))) int i32x2;

__device__ __forceinline__ int cvt_pk_bf16(float lo, float hi) {
    int r;
    asm("v_cvt_pk_bf16_f32 %0, %1, %2" : "=v"(r) : "v"(lo), "v"(hi));
    return r;
}

// async global->LDS, 16B per lane; LDS dest = wave-uniform base + lane*16
__device__ __forceinline__ void stage16(const void* g, void* l) {
    __builtin_amdgcn_global_load_lds(
        (const __attribute__((address_space(1))) void*)g,
        (__attribute__((address_space(3))) void*)l, 16, 0, 0);
}

// ---------------------------------------------------------------------------
// Single fused kernel (ONE dispatch -- removes ~10-15us/node replay tax).
// Grid 512 x 512 threads, 2 blocks/CU co-resident (16 waves/CU, 66KB LDS/CU,
// VGPR<=128 via launch_bounds) -- spin-wait is deadlock-free by capacity.
//
// Phase 1 (block bid -> rows [bid*32, bid*32+32), b = bid>>6, jc = bid&63):
//   Wh = h@W (fp32), si2/sj2 (log2e-scaled), WhF pre-fragmented:
//     WhF[((b*64+jc)*4+ob)*512 + lane*8 + e] = bf16(Wh[jc*32+(lane>>4)*8+e]
//                                                    [ob*16+(lane&15)])
//   then threadfence + release-store flag[bid] = MAGIC.
//
// Handshake: flags are LAUNCH-INVARIANT (data identical across replays), so
// replays >= 2 pass instantly and read identical (possibly concurrent) data;
// only the first post-poison launch spins (0xAA != MAGIC).
//
// Phase 2 = round-15 attention verbatim (45.1us best): b2 = bid&7 (XCD
// affinity), i0 = (bid>>3)*32; 8 waves = (j-quarter q) x (row-group rgrp);
// wave-pairs issue identical WhF fragment loads (vL1 dedup); adj via
// global_load_lds staging (swizzle u^(r&7)); 16 dbuf steps of 32 j;
// p = exp2(max(Ci+sj, 0.2*sj+Di)) * (adj>0), fixed row max (lrelu monotone).
// ---------------------------------------------------------------------------
__global__ __launch_bounds__(512, 4) void gat_fused(
    const float* __restrict__ h, const int* __restrict__ adj,
    const float* __restrict__ W, const float* __restrict__ a,
    unsigned short* __restrict__ WhF, float* __restrict__ si2,
    float* __restrict__ sj2, unsigned* __restrict__ flags,
    float* __restrict__ out)
{
    __shared__ char ldsbuf[33280];
    const int tid  = threadIdx.x;
    const int lane = tid & 63;
    const int wave = tid >> 6;                       // 0..7
    const int bid  = blockIdx.x;

    // ================= Phase 1: produce chunk bid =================
    {
        float* h_lds = (float*)ldsbuf;                        // [32][128] 16KB
        float (*wh_lds)[65] = (float(*)[65])(ldsbuf + 16384); // [32][65] 8.3KB
        const long long row0 = (long long)bid * 32;

        const float4* s4 = (const float4*)(h + row0 * 128);
        #pragma unroll
        for (int i = 0; i < 2; ++i) {
            int idx = tid + i * 512;                 // 0..1023 float4s
            float4 v = s4[idx];
            *(float4*)&h_lds[(idx >> 5)*128 + (idx & 31)*4] = v;
        }
        __syncthreads();

        const float a1 = a[lane];
        const float a2 = a[64 + lane];
        float acc[4];
        #pragma unroll
        for (int r = 0; r < 4; ++r) acc[r] = 0.0f;

        for (int f = 0; f < 128; f += 4) {
            const float w0 = W[(f+0)*64 + lane];
            const float w1 = W[(f+1)*64 + lane];
            const float w2 = W[(f+2)*64 + lane];
            const float w3 = W[(f+3)*64 + lane];
            #pragma unroll
            for (int r = 0; r < 4; ++r) {
                const float4 hv = *(const float4*)&h_lds[(wave*4 + r)*128 + f];
                acc[r] = fmaf(hv.x, w0, acc[r]);
                acc[r] = fmaf(hv.y, w1, acc[r]);
                acc[r] = fmaf(hv.z, w2, acc[r]);
                acc[r] = fmaf(hv.w, w3, acc[r]);
            }
        }

        #pragma unroll
        for (int r = 0; r < 4; ++r) {
            const int rr = wave*4 + r;
            wh_lds[rr][lane] = acc[r];
            float s1 = acc[r] * a1;
            float s2 = acc[r] * a2;
            #pragma unroll
            for (int off = 32; off > 0; off >>= 1) {
                s1 += __shfl_xor(s1, off);
                s2 += __shfl_xor(s2, off);
            }
            if (lane == 0) {
                si2[row0 + rr] = s1 * LOG2E;
                sj2[row0 + rr] = s2 * LOG2E;
            }
        }
        __syncthreads();

        // fragment write: U = tid; ob = U>>7, ln = (U>>1)&63, p = U&1
        const long long b  = row0 >> 11;             // bid>>6
        const int jc = bid & 63;
        const int ob = tid >> 7;
        const int ln = (tid >> 1) & 63;
        const int p  = tid & 1;
        const int o  = ob*16 + (ln & 15);
        const int j0 = (ln >> 4)*8 + p*4;
        i32x2 pk;
        pk[0] = cvt_pk_bf16(wh_lds[j0    ][o], wh_lds[j0 + 1][o]);
        pk[1] = cvt_pk_bf16(wh_lds[j0 + 2][o], wh_lds[j0 + 3][o]);
        *(i32x2*)(WhF + ((b*64 + jc)*4 + ob)*512 + ln*8 + p*4) = pk;

        __syncthreads();                             // all LDS reads/stores done
        if (tid == 0) {
            __threadfence();                         // device-scope release
            __hip_atomic_store(&flags[bid], MAGIC, __ATOMIC_RELEASE,
                               __HIP_MEMORY_SCOPE_AGENT);
        }
    }

    // ================= Handshake: wait for read-batch b2 =================
    const int b2 = bid & 7;
    if (wave == 0) {
        const unsigned* fl = flags + b2*64;
        for (;;) {
            unsigned v = __hip_atomic_load(&fl[lane], __ATOMIC_ACQUIRE,
                                           __HIP_MEMORY_SCOPE_AGENT);
            if (__ballot(v == MAGIC) == ~0ull) break;
            __builtin_amdgcn_s_sleep(8);
        }
    }
    __threadfence();                                 // acquire side
    __syncthreads();

    // ================= Phase 2: attention (r15 verbatim) =================
    const int q    = wave >> 1;                      // j-quarter
    const int rgrp = wave & 1;                       // row-group
    const int i0   = (int)((bid >> 3) << 5);         // 32-row i-tile
    const int arow = lane & 15;
    const int g    = lane >> 4;
    const long long bN = (long long)b2 * 2048;
    const int rbase = i0 + rgrp*16;

    const int* asrc0;
    const int* asrc1;
    {
        int r = lane >> 3;
        int u = (lane & 7) ^ (r & 7);
        asrc0 = adj + (bN + rbase + r)*2048 + q*512 + u*4;
        int r2 = 8 + (lane >> 3);
        int u2 = (lane & 7) ^ (r2 & 7);
        asrc1 = adj + (bN + rbase + r2)*2048 + q*512 + u2*4;
    }

    const unsigned short* fbase =
        WhF + ((long long)(b2*64 + q*16) * 4) * 512 + lane*8;

    const float* sjb = sj2 + bN;
    float mx = -INFINITY;
    #pragma unroll 4
    for (int i = 0; i < 32; ++i) mx = fmaxf(mx, sjb[lane + i*64]);
    #pragma unroll
    for (int off = 32; off > 0; off >>= 1) mx = fmaxf(mx, __shfl_xor(mx, off));

    const float si_r = si2[bN + rbase + arow];
    const float u0f  = si_r + mx;
    const float m2   = fmaxf(u0f, ALPHA * u0f);
    const float Ci   = si_r - m2;
    const float Di   = ALPHA * si_r - m2;

    const float* sjq = sjb + q*512 + g*8;

    f32x4 accf[4];
    #pragma unroll
    for (int ob = 0; ob < 4; ++ob) accf[ob] = (f32x4){0.f,0.f,0.f,0.f};
    f32x4 accl = (f32x4){0.f,0.f,0.f,0.f};
    bf16x8 ones;
    #pragma unroll
    for (int k = 0; k < 8; ++k) ones[k] = (short)0x3F80;

    bf16x8 cb0, cb1, cb2, cb3, nb0, nb1, nb2, nb3;

    #define STAGE(S, STEP) { \
        char* base_ = ldsbuf + (S)*16384 + wave*2048; \
        stage16(asrc0 + (STEP)*32, base_); \
        stage16(asrc1 + (STEP)*32, base_ + 1024); \
    }

    #define LOADB(D0, D1, D2, D3, STEP) { \
        D0 = *(const bf16x8*)(fbase + ((STEP)*4 + 0)*512); \
        D1 = *(const bf16x8*)(fbase + ((STEP)*4 + 1)*512); \
        D2 = *(const bf16x8*)(fbase + ((STEP)*4 + 2)*512); \
        D3 = *(const bf16x8*)(fbase + ((STEP)*4 + 3)*512); \
    }

    #define BODY(S, STEP) { \
        const char* ab = ldsbuf + (S)*16384 + wave*2048; \
        const i32x4 A0 = *(const i32x4*)(ab + arow*128 + ((g*2    ) ^ (arow & 7))*16); \
        const i32x4 A1 = *(const i32x4*)(ab + arow*128 + ((g*2 + 1) ^ (arow & 7))*16); \
        const f32x4 S0 = *(const f32x4*)(sjq + (STEP)*32); \
        const f32x4 S1 = *(const f32x4*)(sjq + (STEP)*32 + 4); \
        float p[8]; \
        _Pragma("unroll") \
        for (int e = 0; e < 4; ++e) { \
            float pe = __builtin_amdgcn_exp2f( \
                fmaxf(Ci + S0[e], fmaf(ALPHA, S0[e], Di))); \
            p[e] = (A0[e] > 0) ? pe : 0.0f; \
        } \
        _Pragma("unroll") \
        for (int e = 0; e < 4; ++e) { \
            float pe = __builtin_amdgcn_exp2f( \
                fmaxf(Ci + S1[e], fmaf(ALPHA, S1[e], Di))); \
            p[4+e] = (A1[e] > 0) ? pe : 0.0f; \
        } \
        i32x4 pk_; \
        pk_[0] = cvt_pk_bf16(p[0], p[1]); \
        pk_[1] = cvt_pk_bf16(p[2], p[3]); \
        pk_[2] = cvt_pk_bf16(p[4], p[5]); \
        pk_[3] = cvt_pk_bf16(p[6], p[7]); \
        const bf16x8 pa = __builtin_bit_cast(bf16x8, pk_); \
        accl    = __builtin_amdgcn_mfma_f32_16x16x32_bf16(pa, ones, accl,    0, 0, 0); \
        accf[0] = __builtin_amdgcn_mfma_f32_16x16x32_bf16(pa, cb0, accf[0], 0, 0, 0); \
        accf[1] = __builtin_amdgcn_mfma_f32_16x16x32_bf16(pa, cb1, accf[1], 0, 0, 0); \
        accf[2] = __builtin_amdgcn_mfma_f32_16x16x32_bf16(pa, cb2, accf[2], 0, 0, 0); \
        accf[3] = __builtin_amdgcn_mfma_f32_16x16x32_bf16(pa, cb3, accf[3], 0, 0, 0); \
    }

    // prologue
    STAGE(0, 0);
    LOADB(cb0, cb1, cb2, cb3, 0);
    __syncthreads();

    // main loop: one barrier/step; B-frags prefetched in regs
    int s = 0;
    for (int st = 0; st < 15; ++st) {
        STAGE(s^1, st+1);
        LOADB(nb0, nb1, nb2, nb3, st+1);
        BODY(s, st);
        __syncthreads();
        cb0 = nb0; cb1 = nb1; cb2 = nb2; cb3 = nb3;
        s ^= 1;
    }
    BODY(s, 15);

    // epilogue: combine the 4 quarter partials per row, divide, store
    __syncthreads();
    float* accb = (float*)ldsbuf;             // [4 q][32 i][64 o] = 32KB
    float* lb   = (float*)(ldsbuf + 32768);   // [4 q][32 i] = 512B
    #pragma unroll
    for (int ob = 0; ob < 4; ++ob)
        #pragma unroll
        for (int reg = 0; reg < 4; ++reg)
            accb[(q*32 + rgrp*16 + g*4 + reg)*64 + ob*16 + arow] = accf[ob][reg];
    if (arow == 0) {
        #pragma unroll
        for (int reg = 0; reg < 4; ++reg)
            lb[q*32 + rgrp*16 + g*4 + reg] = accl[reg];
    }
    __syncthreads();

    const int r  = tid >> 4;                  // 0..31
    const int c0 = (tid & 15) * 4;
    const float L = lb[r] + lb[32 + r] + lb[64 + r] + lb[96 + r];
    const float inv = 1.0f / L;
    float4 v;
    v.x = (accb[r*64 + c0 + 0] + accb[(32+r)*64 + c0 + 0]
         + accb[(64+r)*64 + c0 + 0] + accb[(96+r)*64 + c0 + 0]) * inv;
    v.y = (accb[r*64 + c0 + 1] + accb[(32+r)*64 + c0 + 1]
         + accb[(64+r)*64 + c0 + 1] + accb[(96+r)*64 + c0 + 1]) * inv;
    v.z = (accb[r*64 + c0 + 2] + accb[(32+r)*64 + c0 + 2]
         + accb[(64+r)*64 + c0 + 2] + accb[(96+r)*64 + c0 + 2]) * inv;
    v.w = (accb[r*64 + c0 + 3] + accb[(32+r)*64 + c0 + 3]
         + accb[(64+r)*64 + c0 + 3] + accb[(96+r)*64 + c0 + 3]) * inv;
    *(float4*)(out + (bN + i0 + r)*64 + c0) = v;
}

// ---------------------------------------------------------------------------
// ws layout: WhF 2MB | si2 64KB | sj2 64KB | flags 2KB
// ---------------------------------------------------------------------------
extern "C" void kernel_launch(void* const* d_in, const int* in_sizes, int n_in,
                              void* d_out, int out_size, void* d_ws, size_t ws_size,
                              hipStream_t stream) {
    const float* h   = (const float*)d_in[0];
    const int*   adj = (const int*)d_in[1];
    const float* W   = (const float*)d_in[2];
    const float* a   = (const float*)d_in[3];
    float* out = (float*)d_out;

    unsigned short* WhF = (unsigned short*)d_ws;                // 2 MB
    float* si2 = (float*)((char*)d_ws + (size_t)16384*64*2);
    float* sj2 = si2 + 16384;
    unsigned* flags = (unsigned*)(sj2 + 16384);                 // 512 words

    gat_fused<<<512, 512, 0, stream>>>(h, adj, W, a, WhF, si2, sj2, flags, out);
}

// Round 19
// 45.095 us; speedup vs baseline: 10.3589x; 10.3589x over previous
//
#include <hip/hip_runtime.h>
#include <hip/hip_bf16.h>

#define ALPHA 0.2f
#define LOG2E 1.4426950408889634f

typedef __attribute__((ext_vector_type(8))) short bf16x8;
typedef __attribute__((ext_vector_type(4))) float f32x4;
typedef __attribute__((ext_vector_type(4))) int i32x4;

__device__ __forceinline__ int cvt_pk_bf16(float lo, float hi) {
    int r;
    asm("v_cvt_pk_bf16_f32 %0, %1, %2" : "=v"(r) : "v"(lo), "v"(hi));
    return r;
}

// async global->LDS, 16B per lane; LDS dest = wave-uniform base + lane*16
__device__ __forceinline__ void stage16(const void* g, void* l) {
    __builtin_amdgcn_global_load_lds(
        (const __attribute__((address_space(1))) void*)g,
        (__attribute__((address_space(3))) void*)l, 16, 0, 0);
}

// ---------------------------------------------------------------------------
// Kernel A (verified): Wh = h @ W (fp32), si2/sj2 scaled by log2e, Wh emitted
// PRE-FRAGMENTED for the MFMA B operand:
//   WhF[((b*64 + jc)*4 + ob)*512 + lane*8 + e] = bf16(Wh[j][o]),
//   j = jc*32 + (lane>>4)*8 + e, o = ob*16 + (lane&15)
// ---------------------------------------------------------------------------
__global__ __launch_bounds__(256) void gat_precompute(
    const float* __restrict__ h, const float* __restrict__ W,
    const float* __restrict__ a, unsigned short* __restrict__ WhF,
    float* __restrict__ si2, float* __restrict__ sj2)
{
    __shared__ float h_lds[32][128];
    __shared__ float wh_lds[32][65];   // +1 pad
    const int tid  = threadIdx.x;
    const int lane = tid & 63;
    const int wave = tid >> 6;
    const long long row0 = (long long)blockIdx.x * 32;

    {
        const float4* s4 = (const float4*)(h + row0 * 128);
        #pragma unroll
        for (int i = 0; i < 4; ++i) {
            int idx = tid + i * 256;
            float4 v = s4[idx];
            *(float4*)&h_lds[idx >> 5][(idx & 31) * 4] = v;
        }
    }
    __syncthreads();

    const float a1 = a[lane];
    const float a2 = a[64 + lane];
    float acc[8];
    #pragma unroll
    for (int r = 0; r < 8; ++r) acc[r] = 0.0f;

    for (int f = 0; f < 128; f += 4) {
        const float w0 = W[(f+0)*64 + lane];
        const float w1 = W[(f+1)*64 + lane];
        const float w2 = W[(f+2)*64 + lane];
        const float w3 = W[(f+3)*64 + lane];
        #pragma unroll
        for (int r = 0; r < 8; ++r) {
            const float4 hv = *(const float4*)&h_lds[wave*8 + r][f];
            acc[r] = fmaf(hv.x, w0, acc[r]);
            acc[r] = fmaf(hv.y, w1, acc[r]);
            acc[r] = fmaf(hv.z, w2, acc[r]);
            acc[r] = fmaf(hv.w, w3, acc[r]);
        }
    }

    #pragma unroll
    for (int r = 0; r < 8; ++r) {
        const int rr = wave*8 + r;
        wh_lds[rr][lane] = acc[r];
        float s1 = acc[r] * a1;
        float s2 = acc[r] * a2;
        #pragma unroll
        for (int off = 32; off > 0; off >>= 1) {
            s1 += __shfl_xor(s1, off);
            s2 += __shfl_xor(s2, off);
        }
        if (lane == 0) {
            si2[row0 + rr] = s1 * LOG2E;
            sj2[row0 + rr] = s2 * LOG2E;
        }
    }
    __syncthreads();

    // fragment write: tid = ob*64 + lane
    const long long b  = row0 >> 11;
    const int jcb  = (int)((row0 & 2047) >> 5);   // j-chunk within batch
    const int ob   = tid >> 6;
    const int ln   = tid & 63;
    const int ar   = ln & 15;
    const int gg   = ln >> 4;
    i32x4 pk;
    #pragma unroll
    for (int k = 0; k < 4; ++k)
        pk[k] = cvt_pk_bf16(wh_lds[gg*8 + 2*k    ][ob*16 + ar],
                            wh_lds[gg*8 + 2*k + 1][ob*16 + ar]);
    *(i32x4*)(WhF + ((b*64 + jcb)*4 + ob)*512 + ln*8) = pk;
}

// ---------------------------------------------------------------------------
// Kernel B (round-15 best, 45.0-45.2us, reproduced 3x): round-11 wave-level
// structure, 512-thread blocks (8 waves) cover 32 i-rows: wave = (j-quarter
// q) x (row-group rgrp). The two waves of a quarter issue IDENTICAL WhF
// fragment loads per step (barrier-locked) -> vL1 dedup. Grid 512
// (b = bid&7 -> XCD affinity).
//  - adj: global_load_lds staging, 2KB/wave/step (verified swizzle u^(r&7))
//  - Wh:  pre-fragmented global B-fragments, prefetched 1 step ahead in regs
//  - sj:  direct per-lane loads (L1-hot)
// p = exp2(max(Ci+sj, 0.2*sj+Di)) * (adj>0), fixed row max (lrelu monotone).
// ---------------------------------------------------------------------------
__global__ __launch_bounds__(512) void gat_attention(
    const int* __restrict__ adj, const unsigned short* __restrict__ WhF,
    const float* __restrict__ si2, const float* __restrict__ sj2,
    float* __restrict__ out)
{
    __shared__ char ldsbuf[33280];  // 2 x [8 wave][2KB] staging; epi 32K+512B
    const int tid  = threadIdx.x;
    const int lane = tid & 63;
    const int wave = tid >> 6;                       // 0..7
    const int q    = wave >> 1;                      // j-quarter
    const int rgrp = wave & 1;                       // row-group
    const int b    = blockIdx.x & 7;                 // batch -> XCD affinity
    const int i0   = (int)((blockIdx.x >> 3) << 5);  // 32-row i-tile
    const int arow = lane & 15;
    const int g    = lane >> 4;
    const long long bN = (long long)b * 2048;
    const int rbase = i0 + rgrp*16;                  // this wave's 16 rows

    // ---- adj staging sources (pre-swizzled: slot pu holds unit pu^(r&7)) --
    const int* asrc0;
    const int* asrc1;
    {
        int r = lane >> 3;
        int u = (lane & 7) ^ (r & 7);
        asrc0 = adj + (bN + rbase + r)*2048 + q*512 + u*4;
        int r2 = 8 + (lane >> 3);
        int u2 = (lane & 7) ^ (r2 & 7);
        asrc1 = adj + (bN + rbase + r2)*2048 + q*512 + u2*4;
    }

    // ---- B-fragment base: frag (st, ob) at fbase + (st*4 + ob)*512 ----
    //      (identical for the wave pair sharing quarter q -> vL1 dedup)
    const unsigned short* fbase =
        WhF + ((long long)(b*64 + q*16) * 4) * 512 + lane*8;

    // ---- per-batch sjmax (block-redundant, once) ----
    const float* sjb = sj2 + bN;
    float mx = -INFINITY;
    #pragma unroll 4
    for (int i = 0; i < 32; ++i) mx = fmaxf(mx, sjb[lane + i*64]);
    #pragma unroll
    for (int off = 32; off > 0; off >>= 1) mx = fmaxf(mx, __shfl_xor(mx, off));

    const float si_r = si2[bN + rbase + arow];     // P-row = arow
    const float u0f  = si_r + mx;
    const float m2   = fmaxf(u0f, ALPHA * u0f);    // fixed row max (log2 dom)
    const float Ci   = si_r - m2;
    const float Di   = ALPHA * si_r - m2;

    const float* sjq = sjb + q*512 + g*8;          // this lane's sj stream

    f32x4 accf[4];
    #pragma unroll
    for (int ob = 0; ob < 4; ++ob) accf[ob] = (f32x4){0.f,0.f,0.f,0.f};
    f32x4 accl = (f32x4){0.f,0.f,0.f,0.f};
    bf16x8 ones;
    #pragma unroll
    for (int k = 0; k < 8; ++k) ones[k] = (short)0x3F80;   // bf16 1.0

    bf16x8 cb0, cb1, cb2, cb3, nb0, nb1, nb2, nb3;

    #define STAGE(S, STEP) { \
        char* base_ = ldsbuf + (S)*16384 + wave*2048; \
        stage16(asrc0 + (STEP)*32, base_); \
        stage16(asrc1 + (STEP)*32, base_ + 1024); \
    }

    #define LOADB(D0, D1, D2, D3, STEP) { \
        D0 = *(const bf16x8*)(fbase + ((STEP)*4 + 0)*512); \
        D1 = *(const bf16x8*)(fbase + ((STEP)*4 + 1)*512); \
        D2 = *(const bf16x8*)(fbase + ((STEP)*4 + 2)*512); \
        D3 = *(const bf16x8*)(fbase + ((STEP)*4 + 3)*512); \
    }

    #define BODY(S, STEP) { \
        const char* ab = ldsbuf + (S)*16384 + wave*2048; \
        const i32x4 A0 = *(const i32x4*)(ab + arow*128 + ((g*2    ) ^ (arow & 7))*16); \
        const i32x4 A1 = *(const i32x4*)(ab + arow*128 + ((g*2 + 1) ^ (arow & 7))*16); \
        const f32x4 S0 = *(const f32x4*)(sjq + (STEP)*32); \
        const f32x4 S1 = *(const f32x4*)(sjq + (STEP)*32 + 4); \
        float p[8]; \
        _Pragma("unroll") \
        for (int e = 0; e < 4; ++e) { \
            float pe = __builtin_amdgcn_exp2f( \
                fmaxf(Ci + S0[e], fmaf(ALPHA, S0[e], Di))); \
            p[e] = (A0[e] > 0) ? pe : 0.0f; \
        } \
        _Pragma("unroll") \
        for (int e = 0; e < 4; ++e) { \
            float pe = __builtin_amdgcn_exp2f( \
                fmaxf(Ci + S1[e], fmaf(ALPHA, S1[e], Di))); \
            p[4+e] = (A1[e] > 0) ? pe : 0.0f; \
        } \
        i32x4 pk_; \
        pk_[0] = cvt_pk_bf16(p[0], p[1]); \
        pk_[1] = cvt_pk_bf16(p[2], p[3]); \
        pk_[2] = cvt_pk_bf16(p[4], p[5]); \
        pk_[3] = cvt_pk_bf16(p[6], p[7]); \
        const bf16x8 pa = __builtin_bit_cast(bf16x8, pk_); \
        accl    = __builtin_amdgcn_mfma_f32_16x16x32_bf16(pa, ones, accl,    0, 0, 0); \
        accf[0] = __builtin_amdgcn_mfma_f32_16x16x32_bf16(pa, cb0, accf[0], 0, 0, 0); \
        accf[1] = __builtin_amdgcn_mfma_f32_16x16x32_bf16(pa, cb1, accf[1], 0, 0, 0); \
        accf[2] = __builtin_amdgcn_mfma_f32_16x16x32_bf16(pa, cb2, accf[2], 0, 0, 0); \
        accf[3] = __builtin_amdgcn_mfma_f32_16x16x32_bf16(pa, cb3, accf[3], 0, 0, 0); \
    }

    // ---- prologue ----
    STAGE(0, 0);
    LOADB(cb0, cb1, cb2, cb3, 0);
    __syncthreads();

    // ---- main loop: one barrier/step; B-frags prefetched in regs ----
    int s = 0;
    for (int st = 0; st < 15; ++st) {
        STAGE(s^1, st+1);
        LOADB(nb0, nb1, nb2, nb3, st+1);
        BODY(s, st);
        __syncthreads();
        cb0 = nb0; cb1 = nb1; cb2 = nb2; cb3 = nb3;
        s ^= 1;
    }
    BODY(s, 15);

    // ---- epilogue: combine the 4 quarter partials per row, divide, store --
    __syncthreads();                          // all waves done with adj bufs
    float* accb = (float*)ldsbuf;             // [4 q][32 i][64 o] = 32KB
    float* lb   = (float*)(ldsbuf + 32768);   // [4 q][32 i] = 512B
    #pragma unroll
    for (int ob = 0; ob < 4; ++ob)
        #pragma unroll
        for (int reg = 0; reg < 4; ++reg)
            accb[(q*32 + rgrp*16 + g*4 + reg)*64 + ob*16 + arow] = accf[ob][reg];
    if (arow == 0) {
        #pragma unroll
        for (int reg = 0; reg < 4; ++reg)
            lb[q*32 + rgrp*16 + g*4 + reg] = accl[reg];
    }
    __syncthreads();

    const int r  = tid >> 4;                  // 0..31
    const int c0 = (tid & 15) * 4;
    const float L = lb[r] + lb[32 + r] + lb[64 + r] + lb[96 + r];
    const float inv = 1.0f / L;
    float4 v;
    v.x = (accb[r*64 + c0 + 0] + accb[(32+r)*64 + c0 + 0]
         + accb[(64+r)*64 + c0 + 0] + accb[(96+r)*64 + c0 + 0]) * inv;
    v.y = (accb[r*64 + c0 + 1] + accb[(32+r)*64 + c0 + 1]
         + accb[(64+r)*64 + c0 + 1] + accb[(96+r)*64 + c0 + 1]) * inv;
    v.z = (accb[r*64 + c0 + 2] + accb[(32+r)*64 + c0 + 2]
         + accb[(64+r)*64 + c0 + 2] + accb[(96+r)*64 + c0 + 2]) * inv;
    v.w = (accb[r*64 + c0 + 3] + accb[(32+r)*64 + c0 + 3]
         + accb[(64+r)*64 + c0 + 3] + accb[(96+r)*64 + c0 + 3]) * inv;
    *(float4*)(out + (bN + i0 + r)*64 + c0) = v;
}

// ---------------------------------------------------------------------------
// ws layout: WhF 2MB | si2 64KB | sj2 64KB
// ---------------------------------------------------------------------------
extern "C" void kernel_launch(void* const* d_in, const int* in_sizes, int n_in,
                              void* d_out, int out_size, void* d_ws, size_t ws_size,
                              hipStream_t stream) {
    const float* h   = (const float*)d_in[0];
    const int*   adj = (const int*)d_in[1];
    const float* W   = (const float*)d_in[2];
    const float* a   = (const float*)d_in[3];
    float* out = (float*)d_out;

    unsigned short* WhF = (unsigned short*)d_ws;                // 2 MB
    float* si2 = (float*)((char*)d_ws + (size_t)16384*64*2);
    float* sj2 = si2 + 16384;

    gat_precompute<<<512, 256, 0, stream>>>(h, W, a, WhF, si2, sj2);
    gat_attention<<<512, 512, 0, stream>>>(adj, WhF, si2, sj2, out);
}